// Round 1
// baseline (4370.420 us; speedup 1.0000x reference)
//
#include <hip/hip_runtime.h>
#include <cstdint>

// ---------------------------------------------------------------------------
// DiffusionLayer: 3x GATv2 (rate: user->item, ratedby: item->user,
// trust: user->user) + attention-gated fusion.
// All f32. D = 64 fixed.
// ---------------------------------------------------------------------------

#define D 64

__device__ __forceinline__ float waveReduceSum(float v) {
#pragma unroll
  for (int off = 32; off > 0; off >>= 1) v += __shfl_xor(v, off, 64);
  return v;
}

// ---- projection: Y = X @ W + b;  X[N,64], W[64,64] row-major, b[64] -------
__global__ __launch_bounds__(256) void proj64_kernel(
    const float* __restrict__ X, const float* __restrict__ W,
    const float* __restrict__ b, float* __restrict__ Y, int N) {
  __shared__ __align__(16) float Ws[64 * 64];
  __shared__ float Xs[64][66];  // stride 66: staging writes & reads conflict-light
  const int t = threadIdx.x;
  const int row0 = blockIdx.x * 64;

#pragma unroll
  for (int i = 0; i < 16; ++i) Ws[t + i * 256] = W[t + i * 256];
#pragma unroll
  for (int i = 0; i < 16; ++i) {
    int idx = t + i * 256;  // 0..4095
    int r = idx >> 6, k = idx & 63;
    int gr = row0 + r;
    Xs[r][k] = (gr < N) ? X[gr * 64 + k] : 0.f;
  }
  __syncthreads();

  const int jt = (t & 15) * 4;  // column group (4 cols)
  const int rt = (t >> 4) * 4;  // row group (4 rows)
  float4 bb = *reinterpret_cast<const float4*>(b + jt);
  float a00 = bb.x, a01 = bb.y, a02 = bb.z, a03 = bb.w;
  float a10 = bb.x, a11 = bb.y, a12 = bb.z, a13 = bb.w;
  float a20 = bb.x, a21 = bb.y, a22 = bb.z, a23 = bb.w;
  float a30 = bb.x, a31 = bb.y, a32 = bb.z, a33 = bb.w;

#pragma unroll 8
  for (int k = 0; k < 64; ++k) {
    float4 w4 = *reinterpret_cast<const float4*>(&Ws[k * 64 + jt]);
    float x0 = Xs[rt + 0][k];
    float x1 = Xs[rt + 1][k];
    float x2 = Xs[rt + 2][k];
    float x3 = Xs[rt + 3][k];
    a00 += x0 * w4.x; a01 += x0 * w4.y; a02 += x0 * w4.z; a03 += x0 * w4.w;
    a10 += x1 * w4.x; a11 += x1 * w4.y; a12 += x1 * w4.z; a13 += x1 * w4.w;
    a20 += x2 * w4.x; a21 += x2 * w4.y; a22 += x2 * w4.z; a23 += x2 * w4.w;
    a30 += x3 * w4.x; a31 += x3 * w4.y; a32 += x3 * w4.z; a33 += x3 * w4.w;
  }

  float4 o0 = {a00, a01, a02, a03};
  float4 o1 = {a10, a11, a12, a13};
  float4 o2 = {a20, a21, a22, a23};
  float4 o3 = {a30, a31, a32, a33};
  int gr = row0 + rt;
  if (gr + 0 < N) *reinterpret_cast<float4*>(&Y[(gr + 0) * 64 + jt]) = o0;
  if (gr + 1 < N) *reinterpret_cast<float4*>(&Y[(gr + 1) * 64 + jt]) = o1;
  if (gr + 2 < N) *reinterpret_cast<float4*>(&Y[(gr + 2) * 64 + jt]) = o2;
  if (gr + 3 < N) *reinterpret_cast<float4*>(&Y[(gr + 3) * 64 + jt]) = o3;
}

// ---- pass A: e[i] = leakyrelu(fs[src]+fd[dst],0.2) . attn ; segment max ----
__device__ __forceinline__ unsigned mapFloat(float x) {
  unsigned u = __float_as_uint(x);
  return (u >> 31) ? ~u : (u | 0x80000000u);
}
__device__ __forceinline__ float unmapFloat(unsigned m) {
  return (m & 0x80000000u) ? __uint_as_float(m ^ 0x80000000u)
                           : __uint_as_float(~m);
}

__global__ __launch_bounds__(256) void edge_scores_kernel(
    const float* __restrict__ fs, const float* __restrict__ fd,
    const int* __restrict__ src, const int* __restrict__ dst,
    const float* __restrict__ attn, float* __restrict__ e,
    unsigned* __restrict__ m, int E) {
  int widx = (blockIdx.x * 256 + threadIdx.x) >> 6;
  int lane = threadIdx.x & 63;
  if (widx >= E) return;
  int s = src[widx];
  int d = dst[widx];
  float v = fs[s * 64 + lane] + fd[d * 64 + lane];
  v = (v > 0.f) ? v : 0.2f * v;
  v *= attn[lane];
  v = waveReduceSum(v);
  if (lane == 0) {
    e[widx] = v;
    atomicMax(&m[d], mapFloat(v));
  }
}

// ---- pass B: a = exp(e - m[dst]); z[dst]+=a; acc[dst,:] += a*fs[src,:] ----
__global__ __launch_bounds__(256) void edge_accum_kernel(
    const float* __restrict__ fs, const int* __restrict__ src,
    const int* __restrict__ dst, const float* __restrict__ e,
    const unsigned* __restrict__ m, float* __restrict__ z,
    float* __restrict__ acc, int E) {
  int widx = (blockIdx.x * 256 + threadIdx.x) >> 6;
  int lane = threadIdx.x & 63;
  if (widx >= E) return;
  int s = src[widx];
  int d = dst[widx];
  float mx = unmapFloat(m[d]);
  float a = expf(e[widx] - mx);
  atomicAdd(&acc[d * 64 + lane], a * fs[s * 64 + lane]);
  if (lane == 0) atomicAdd(&z[d], a);
}

// ---- finalize: out = acc / z + bias (+ optional residual) -----------------
__global__ __launch_bounds__(256) void finalize_kernel(
    const float* __restrict__ acc, const float* __restrict__ z,
    const float* __restrict__ bias, const float* __restrict__ resid,
    float* __restrict__ out, int total) {
  int i = blockIdx.x * 256 + threadIdx.x;
  if (i >= total) return;
  int n = i >> 6, k = i & 63;
  float zz = z[n];
  float inv = (zz > 0.f) ? 1.f / zz : 0.f;
  float v = acc[i] * inv + bias[k];
  if (resid) v += resid[i];
  out[i] = v;
}

// ---- collapse Linear(128,128)->Linear(128,1) into one 128-vector ----------
// wbuf layout: [0..127]=w_inf, [128]=c_inf, [130..257]=w_int, [258]=c_int
__global__ __launch_bounds__(256) void weff_kernel(
    const float* __restrict__ W1i, const float* __restrict__ b1i,
    const float* __restrict__ W2i, const float* __restrict__ b2i,
    const float* __restrict__ W1t, const float* __restrict__ b1t,
    const float* __restrict__ W2t, const float* __restrict__ b2t,
    float* __restrict__ wbuf) {
  int t = threadIdx.x;
  const float* W1 = (t < 128) ? W1i : W1t;
  const float* W2 = (t < 128) ? W2i : W2t;
  int i = t & 127;
  int base = (t < 128) ? 0 : 130;
  float s = 0.f;
  for (int j = 0; j < 128; ++j) s += W1[i * 128 + j] * W2[j];
  wbuf[base + i] = s;
  if (i == 0) {
    const float* b1 = (t < 128) ? b1i : b1t;
    const float* b2 = (t < 128) ? b2i : b2t;
    float c = b2[0];
    for (int j = 0; j < 128; ++j) c += b1[j] * W2[j];
    wbuf[base + 128] = c;
  }
}

// ---- h_inf/h_int per user + BN statistics (double atomics) ----------------
__global__ __launch_bounds__(256) void fuse_h_kernel(
    const float* __restrict__ ue, const float* __restrict__ p,
    const float* __restrict__ q, const float* __restrict__ wbuf,
    float* __restrict__ h_inf, float* __restrict__ h_int,
    double* __restrict__ stats, int NU) {
  __shared__ float sh[16];  // [0:4) hi, [4:8) hi^2, [8:12) ht, [12:16) ht^2
  int gtid = blockIdx.x * 256 + threadIdx.x;
  int u = gtid >> 6;
  int lane = threadIdx.x & 63;
  int wv = threadIdx.x >> 6;
  float hi = 0.f, ht = 0.f;
  if (u < NU) {
    float uv = ue[u * 64 + lane];
    hi = uv * wbuf[lane] + p[u * 64 + lane] * wbuf[64 + lane];
    ht = uv * wbuf[130 + lane] + q[u * 64 + lane] * wbuf[194 + lane];
  }
  hi = waveReduceSum(hi);
  ht = waveReduceSum(ht);
  if (lane == 0) {
    if (u < NU) {
      hi += wbuf[128];
      ht += wbuf[258];
      h_inf[u] = hi;
      h_int[u] = ht;
    } else {
      hi = 0.f;
      ht = 0.f;
    }
    sh[wv] = hi;
    sh[4 + wv] = hi * hi;
    sh[8 + wv] = ht;
    sh[12 + wv] = ht * ht;
  }
  __syncthreads();
  if (threadIdx.x == 0) {
    atomicAdd(&stats[0], (double)(sh[0] + sh[1] + sh[2] + sh[3]));
    atomicAdd(&stats[1], (double)(sh[4] + sh[5] + sh[6] + sh[7]));
    atomicAdd(&stats[2], (double)(sh[8] + sh[9] + sh[10] + sh[11]));
    atomicAdd(&stats[3], (double)(sh[12] + sh[13] + sh[14] + sh[15]));
  }
}

// ---- final: BN + leaky + 2-way softmax + gated sum + residual -------------
__global__ __launch_bounds__(256) void fuse_out_kernel(
    const float* __restrict__ ue, const float* __restrict__ p,
    const float* __restrict__ q, const float* __restrict__ h_inf,
    const float* __restrict__ h_int, const double* __restrict__ stats,
    const float* __restrict__ gi, const float* __restrict__ bei,
    const float* __restrict__ gt, const float* __restrict__ bet,
    float* __restrict__ out, int NU) {
  int i = blockIdx.x * 256 + threadIdx.x;
  if (i >= NU * 64) return;
  int u = i >> 6;
  double invN = 1.0 / (double)NU;
  float mu_i = (float)(stats[0] * invN);
  float var_i = (float)(stats[1] * invN) - mu_i * mu_i;
  float mu_t = (float)(stats[2] * invN);
  float var_t = (float)(stats[3] * invN) - mu_t * mu_t;
  float si = gi[0] * (h_inf[u] - mu_i) / sqrtf(var_i + 1e-5f) + bei[0];
  si = (si > 0.f) ? si : 0.01f * si;
  float st = gt[0] * (h_int[u] - mu_t) / sqrtf(var_t + 1e-5f) + bet[0];
  st = (st > 0.f) ? st : 0.01f * st;
  float mx = fmaxf(si, st);
  float e0 = expf(si - mx), e1 = expf(st - mx);
  float inv = 1.f / (e0 + e1);
  out[i] = (e0 * inv) * p[i] + (e1 * inv) * q[i] + ue[i];
}

// ---------------------------------------------------------------------------
extern "C" void kernel_launch(void* const* d_in, const int* in_sizes, int n_in,
                              void* d_out, int out_size, void* d_ws,
                              size_t ws_size, hipStream_t stream) {
  // inputs in setup_inputs() order
  const float* user_emb = (const float*)d_in[0];
  const float* item_emb = (const float*)d_in[1];
  const int* rate_src = (const int*)d_in[2];
  const int* rate_dst = (const int*)d_in[3];
  const int* rb_src = (const int*)d_in[4];
  const int* rb_dst = (const int*)d_in[5];
  const int* tr_src = (const int*)d_in[6];
  const int* tr_dst = (const int*)d_in[7];
  const float* rate_Wsrc = (const float*)d_in[8];
  const float* rate_bsrc = (const float*)d_in[9];
  const float* rate_Wdst = (const float*)d_in[10];
  const float* rate_bdst = (const float*)d_in[11];
  const float* rate_attn = (const float*)d_in[12];
  const float* rate_bias = (const float*)d_in[13];
  const float* rb_Wsrc = (const float*)d_in[14];
  const float* rb_bsrc = (const float*)d_in[15];
  const float* rb_Wdst = (const float*)d_in[16];
  const float* rb_bdst = (const float*)d_in[17];
  const float* rb_attn = (const float*)d_in[18];
  const float* rb_bias = (const float*)d_in[19];
  const float* tr_Wsrc = (const float*)d_in[20];
  const float* tr_bsrc = (const float*)d_in[21];
  const float* tr_Wdst = (const float*)d_in[22];
  const float* tr_bdst = (const float*)d_in[23];
  const float* tr_attn = (const float*)d_in[24];
  const float* tr_bias = (const float*)d_in[25];
  const float* inf_W1 = (const float*)d_in[26];
  const float* inf_b1 = (const float*)d_in[27];
  const float* inf_W2 = (const float*)d_in[28];
  const float* inf_b2 = (const float*)d_in[29];
  const float* inf_g = (const float*)d_in[30];
  const float* inf_be = (const float*)d_in[31];
  const float* int_W1 = (const float*)d_in[32];
  const float* int_b1 = (const float*)d_in[33];
  const float* int_W2 = (const float*)d_in[34];
  const float* int_b2 = (const float*)d_in[35];
  const float* int_g = (const float*)d_in[36];
  const float* int_be = (const float*)d_in[37];

  const int NU = in_sizes[0] / 64;
  const int NI = in_sizes[1] / 64;
  const int E = in_sizes[2];
  const size_t MX = (size_t)((NU > NI) ? NU : NI);

  // workspace carve-up (256B aligned)
  char* ws = (char*)d_ws;
  size_t off = 0;
  auto alloc = [&](size_t bytes) -> void* {
    void* pp = ws + off;
    off += (bytes + 255) & ~(size_t)255;
    return pp;
  };
  float* fs = (float*)alloc(MX * 64 * 4);
  float* fd = (float*)alloc(MX * 64 * 4);
  float* q_acc = (float*)alloc((size_t)NU * 64 * 4);
  float* e_buf = (float*)alloc((size_t)E * 4);
  unsigned* m_buf = (unsigned*)alloc(MX * 4);
  float* z_buf = (float*)alloc(MX * 4);
  float* h_inf = (float*)alloc((size_t)NU * 4);
  float* h_int = (float*)alloc((size_t)NU * 4);
  float* wbuf = (float*)alloc(272 * 4);
  double* stats = (double*)alloc(4 * 8);

  float* p_acc = (float*)d_out;                 // user region of output
  float* item_acc = (float*)d_out + (size_t)NU * 64;  // item region

  const int projThreads = 256;
  auto projGrid = [](int n) { return (n + 63) / 64; };
  const int edgeBlocks = (E + 3) / 4;  // 4 waves/block, 1 edge/wave
  auto elemGrid = [](int total) { return (total + 255) / 256; };

  // zero accumulators
  hipMemsetAsync(d_out, 0, (size_t)out_size * sizeof(float), stream);
  hipMemsetAsync(q_acc, 0, (size_t)NU * 64 * 4, stream);
  hipMemsetAsync(stats, 0, 4 * 8, stream);

  weff_kernel<<<1, 256, 0, stream>>>(inf_W1, inf_b1, inf_W2, inf_b2, int_W1,
                                     int_b1, int_W2, int_b2, wbuf);

  // ---- trust: user -> user  => p_hair (in d_out user region) ----
  proj64_kernel<<<projGrid(NU), projThreads, 0, stream>>>(user_emb, tr_Wsrc,
                                                          tr_bsrc, fs, NU);
  proj64_kernel<<<projGrid(NU), projThreads, 0, stream>>>(user_emb, tr_Wdst,
                                                          tr_bdst, fd, NU);
  hipMemsetAsync(m_buf, 0, MX * 4, stream);
  hipMemsetAsync(z_buf, 0, MX * 4, stream);
  edge_scores_kernel<<<edgeBlocks, 256, 0, stream>>>(fs, fd, tr_src, tr_dst,
                                                     tr_attn, e_buf, m_buf, E);
  edge_accum_kernel<<<edgeBlocks, 256, 0, stream>>>(fs, tr_src, tr_dst, e_buf,
                                                    m_buf, z_buf, p_acc, E);
  finalize_kernel<<<elemGrid(NU * 64), 256, 0, stream>>>(
      p_acc, z_buf, tr_bias, nullptr, p_acc, NU * 64);

  // ---- ratedby: item -> user  => q_hair ----
  proj64_kernel<<<projGrid(NI), projThreads, 0, stream>>>(item_emb, rb_Wsrc,
                                                          rb_bsrc, fs, NI);
  proj64_kernel<<<projGrid(NU), projThreads, 0, stream>>>(user_emb, rb_Wdst,
                                                          rb_bdst, fd, NU);
  hipMemsetAsync(m_buf, 0, MX * 4, stream);
  hipMemsetAsync(z_buf, 0, MX * 4, stream);
  edge_scores_kernel<<<edgeBlocks, 256, 0, stream>>>(fs, fd, rb_src, rb_dst,
                                                     rb_attn, e_buf, m_buf, E);
  edge_accum_kernel<<<edgeBlocks, 256, 0, stream>>>(fs, rb_src, rb_dst, e_buf,
                                                    m_buf, z_buf, q_acc, E);
  finalize_kernel<<<elemGrid(NU * 64), 256, 0, stream>>>(
      q_acc, z_buf, rb_bias, nullptr, q_acc, NU * 64);

  // ---- rate: user -> item  => item_out (d_out item region) ----
  proj64_kernel<<<projGrid(NU), projThreads, 0, stream>>>(user_emb, rate_Wsrc,
                                                          rate_bsrc, fs, NU);
  proj64_kernel<<<projGrid(NI), projThreads, 0, stream>>>(item_emb, rate_Wdst,
                                                          rate_bdst, fd, NI);
  hipMemsetAsync(m_buf, 0, MX * 4, stream);
  hipMemsetAsync(z_buf, 0, MX * 4, stream);
  edge_scores_kernel<<<edgeBlocks, 256, 0, stream>>>(
      fs, fd, rate_src, rate_dst, rate_attn, e_buf, m_buf, E);
  edge_accum_kernel<<<edgeBlocks, 256, 0, stream>>>(
      fs, rate_src, rate_dst, e_buf, m_buf, z_buf, item_acc, E);
  finalize_kernel<<<elemGrid(NI * 64), 256, 0, stream>>>(
      item_acc, z_buf, rate_bias, item_emb, item_acc, NI * 64);

  // ---- fusion ----
  fuse_h_kernel<<<(NU + 3) / 4, 256, 0, stream>>>(user_emb, p_acc, q_acc, wbuf,
                                                  h_inf, h_int, stats, NU);
  fuse_out_kernel<<<elemGrid(NU * 64), 256, 0, stream>>>(
      user_emb, p_acc, q_acc, h_inf, h_int, stats, inf_g, inf_be, int_g,
      int_be, (float*)d_out, NU);
}

// Round 3
// 1997.663 us; speedup vs baseline: 2.1878x; 2.1878x over previous
//
#include <hip/hip_runtime.h>
#include <cstdint>

// ---------------------------------------------------------------------------
// DiffusionLayer: 3x GATv2 (rate: user->item, ratedby: item->user,
// trust: user->user) + attention-gated fusion.
// All f32. D = 64 fixed.
// R2 (resubmitted R3; R2 bench hit GPUAcquisitionTimeout):
//     fuse_h rewritten grid-stride + two-stage (non-atomic) BN-stat
//     reduction. R1 profile showed 50K blocks x 4 double atomicAdds to the
//     same 4 addresses = 2.4 ms of serialization (55% of total).
// ---------------------------------------------------------------------------

#define D 64
#define FH_BLOCKS 1024  // fuse_h grid; partials reduced by reduce_stats_kernel

__device__ __forceinline__ float waveReduceSum(float v) {
#pragma unroll
  for (int off = 32; off > 0; off >>= 1) v += __shfl_xor(v, off, 64);
  return v;
}

// ---- projection: Y = X @ W + b;  X[N,64], W[64,64] row-major, b[64] -------
__global__ __launch_bounds__(256) void proj64_kernel(
    const float* __restrict__ X, const float* __restrict__ W,
    const float* __restrict__ b, float* __restrict__ Y, int N) {
  __shared__ __align__(16) float Ws[64 * 64];
  __shared__ float Xs[64][66];
  const int t = threadIdx.x;
  const int row0 = blockIdx.x * 64;

#pragma unroll
  for (int i = 0; i < 16; ++i) Ws[t + i * 256] = W[t + i * 256];
#pragma unroll
  for (int i = 0; i < 16; ++i) {
    int idx = t + i * 256;  // 0..4095
    int r = idx >> 6, k = idx & 63;
    int gr = row0 + r;
    Xs[r][k] = (gr < N) ? X[gr * 64 + k] : 0.f;
  }
  __syncthreads();

  const int jt = (t & 15) * 4;  // column group (4 cols)
  const int rt = (t >> 4) * 4;  // row group (4 rows)
  float4 bb = *reinterpret_cast<const float4*>(b + jt);
  float a00 = bb.x, a01 = bb.y, a02 = bb.z, a03 = bb.w;
  float a10 = bb.x, a11 = bb.y, a12 = bb.z, a13 = bb.w;
  float a20 = bb.x, a21 = bb.y, a22 = bb.z, a23 = bb.w;
  float a30 = bb.x, a31 = bb.y, a32 = bb.z, a33 = bb.w;

#pragma unroll 8
  for (int k = 0; k < 64; ++k) {
    float4 w4 = *reinterpret_cast<const float4*>(&Ws[k * 64 + jt]);
    float x0 = Xs[rt + 0][k];
    float x1 = Xs[rt + 1][k];
    float x2 = Xs[rt + 2][k];
    float x3 = Xs[rt + 3][k];
    a00 += x0 * w4.x; a01 += x0 * w4.y; a02 += x0 * w4.z; a03 += x0 * w4.w;
    a10 += x1 * w4.x; a11 += x1 * w4.y; a12 += x1 * w4.z; a13 += x1 * w4.w;
    a20 += x2 * w4.x; a21 += x2 * w4.y; a22 += x2 * w4.z; a23 += x2 * w4.w;
    a30 += x3 * w4.x; a31 += x3 * w4.y; a32 += x3 * w4.z; a33 += x3 * w4.w;
  }

  float4 o0 = {a00, a01, a02, a03};
  float4 o1 = {a10, a11, a12, a13};
  float4 o2 = {a20, a21, a22, a23};
  float4 o3 = {a30, a31, a32, a33};
  int gr = row0 + rt;
  if (gr + 0 < N) *reinterpret_cast<float4*>(&Y[(gr + 0) * 64 + jt]) = o0;
  if (gr + 1 < N) *reinterpret_cast<float4*>(&Y[(gr + 1) * 64 + jt]) = o1;
  if (gr + 2 < N) *reinterpret_cast<float4*>(&Y[(gr + 2) * 64 + jt]) = o2;
  if (gr + 3 < N) *reinterpret_cast<float4*>(&Y[(gr + 3) * 64 + jt]) = o3;
}

// ---- pass A: e[i] = leakyrelu(fs[src]+fd[dst],0.2) . attn ; segment max ----
__device__ __forceinline__ unsigned mapFloat(float x) {
  unsigned u = __float_as_uint(x);
  return (u >> 31) ? ~u : (u | 0x80000000u);
}
__device__ __forceinline__ float unmapFloat(unsigned m) {
  return (m & 0x80000000u) ? __uint_as_float(m ^ 0x80000000u)
                           : __uint_as_float(~m);
}

__global__ __launch_bounds__(256) void edge_scores_kernel(
    const float* __restrict__ fs, const float* __restrict__ fd,
    const int* __restrict__ src, const int* __restrict__ dst,
    const float* __restrict__ attn, float* __restrict__ e,
    unsigned* __restrict__ m, int E) {
  int widx = (blockIdx.x * 256 + threadIdx.x) >> 6;
  int lane = threadIdx.x & 63;
  if (widx >= E) return;
  int s = src[widx];
  int d = dst[widx];
  float v = fs[s * 64 + lane] + fd[d * 64 + lane];
  v = (v > 0.f) ? v : 0.2f * v;
  v *= attn[lane];
  v = waveReduceSum(v);
  if (lane == 0) {
    e[widx] = v;
    atomicMax(&m[d], mapFloat(v));
  }
}

// ---- pass B: a = exp(e - m[dst]); z[dst]+=a; acc[dst,:] += a*fs[src,:] ----
__global__ __launch_bounds__(256) void edge_accum_kernel(
    const float* __restrict__ fs, const int* __restrict__ src,
    const int* __restrict__ dst, const float* __restrict__ e,
    const unsigned* __restrict__ m, float* __restrict__ z,
    float* __restrict__ acc, int E) {
  int widx = (blockIdx.x * 256 + threadIdx.x) >> 6;
  int lane = threadIdx.x & 63;
  if (widx >= E) return;
  int s = src[widx];
  int d = dst[widx];
  float mx = unmapFloat(m[d]);
  float a = expf(e[widx] - mx);
  atomicAdd(&acc[d * 64 + lane], a * fs[s * 64 + lane]);
  if (lane == 0) atomicAdd(&z[d], a);
}

// ---- finalize: out = acc / z + bias (+ optional residual) -----------------
__global__ __launch_bounds__(256) void finalize_kernel(
    const float* __restrict__ acc, const float* __restrict__ z,
    const float* __restrict__ bias, const float* __restrict__ resid,
    float* __restrict__ out, int total) {
  int i = blockIdx.x * 256 + threadIdx.x;
  if (i >= total) return;
  int n = i >> 6, k = i & 63;
  float zz = z[n];
  float inv = (zz > 0.f) ? 1.f / zz : 0.f;
  float v = acc[i] * inv + bias[k];
  if (resid) v += resid[i];
  out[i] = v;
}

// ---- collapse Linear(128,128)->Linear(128,1) into one 128-vector ----------
// wbuf layout: [0..127]=w_inf, [128]=c_inf, [130..257]=w_int, [258]=c_int
__global__ __launch_bounds__(256) void weff_kernel(
    const float* __restrict__ W1i, const float* __restrict__ b1i,
    const float* __restrict__ W2i, const float* __restrict__ b2i,
    const float* __restrict__ W1t, const float* __restrict__ b1t,
    const float* __restrict__ W2t, const float* __restrict__ b2t,
    float* __restrict__ wbuf) {
  int t = threadIdx.x;
  const float* W1 = (t < 128) ? W1i : W1t;
  const float* W2 = (t < 128) ? W2i : W2t;
  int i = t & 127;
  int base = (t < 128) ? 0 : 130;
  float s = 0.f;
  for (int j = 0; j < 128; ++j) s += W1[i * 128 + j] * W2[j];
  wbuf[base + i] = s;
  if (i == 0) {
    const float* b1 = (t < 128) ? b1i : b1t;
    const float* b2 = (t < 128) ? b2i : b2t;
    float c = b2[0];
    for (int j = 0; j < 128; ++j) c += b1[j] * W2[j];
    wbuf[base + 128] = c;
  }
}

// ---- h_inf/h_int per user + per-block BN partial sums (NO atomics) --------
// partials layout: [block][4] doubles = {sum hi, sum hi^2, sum ht, sum ht^2}
__global__ __launch_bounds__(256) void fuse_h_kernel(
    const float* __restrict__ ue, const float* __restrict__ p,
    const float* __restrict__ q, const float* __restrict__ wbuf,
    float* __restrict__ h_inf, float* __restrict__ h_int,
    double* __restrict__ partials, int NU) {
  const int lane = threadIdx.x & 63;
  const int wv = threadIdx.x >> 6;
  const int wave = blockIdx.x * 4 + wv;
  const int nwaves = gridDim.x * 4;

  const float wi_u = wbuf[lane];
  const float wi_p = wbuf[64 + lane];
  const float wt_u = wbuf[130 + lane];
  const float wt_q = wbuf[194 + lane];
  const float ci = wbuf[128];
  const float ct = wbuf[258];

  double s0 = 0., s1 = 0., s2 = 0., s3 = 0.;
  for (int u = wave; u < NU; u += nwaves) {
    float uv = ue[u * 64 + lane];
    float hi = uv * wi_u + p[u * 64 + lane] * wi_p;
    float ht = uv * wt_u + q[u * 64 + lane] * wt_q;
    hi = waveReduceSum(hi) + ci;  // butterfly: all lanes hold the sum
    ht = waveReduceSum(ht) + ct;
    if (lane == 0) {
      h_inf[u] = hi;
      h_int[u] = ht;
    }
    s0 += (double)hi;
    s1 += (double)hi * (double)hi;
    s2 += (double)ht;
    s3 += (double)ht * (double)ht;
  }

  __shared__ double sh[4][4];
  if (lane == 0) {
    sh[wv][0] = s0;
    sh[wv][1] = s1;
    sh[wv][2] = s2;
    sh[wv][3] = s3;
  }
  __syncthreads();
  if (threadIdx.x < 4) {
    int k = threadIdx.x;
    partials[blockIdx.x * 4 + k] = sh[0][k] + sh[1][k] + sh[2][k] + sh[3][k];
  }
}

// ---- single-block reduction of fuse_h partials -> stats[4] ----------------
__global__ __launch_bounds__(256) void reduce_stats_kernel(
    const double* __restrict__ partials, double* __restrict__ stats,
    int nblocks) {
  int k = threadIdx.x & 3;
  int bstart = threadIdx.x >> 2;  // 0..63
  double s = 0.;
  for (int b = bstart; b < nblocks; b += 64) s += partials[b * 4 + k];
  __shared__ double sh[256];
  sh[threadIdx.x] = s;
  __syncthreads();
  if (threadIdx.x < 4) {
    double acc = 0.;
    for (int i = 0; i < 64; ++i) acc += sh[i * 4 + threadIdx.x];
    stats[threadIdx.x] = acc;
  }
}

// ---- final: BN + leaky + 2-way softmax + gated sum + residual -------------
__global__ __launch_bounds__(256) void fuse_out_kernel(
    const float* __restrict__ ue, const float* __restrict__ p,
    const float* __restrict__ q, const float* __restrict__ h_inf,
    const float* __restrict__ h_int, const double* __restrict__ stats,
    const float* __restrict__ gi, const float* __restrict__ bei,
    const float* __restrict__ gt, const float* __restrict__ bet,
    float* __restrict__ out, int NU) {
  int i = blockIdx.x * 256 + threadIdx.x;
  if (i >= NU * 64) return;
  int u = i >> 6;
  double invN = 1.0 / (double)NU;
  float mu_i = (float)(stats[0] * invN);
  float var_i = (float)(stats[1] * invN) - mu_i * mu_i;
  float mu_t = (float)(stats[2] * invN);
  float var_t = (float)(stats[3] * invN) - mu_t * mu_t;
  float si = gi[0] * (h_inf[u] - mu_i) / sqrtf(var_i + 1e-5f) + bei[0];
  si = (si > 0.f) ? si : 0.01f * si;
  float st = gt[0] * (h_int[u] - mu_t) / sqrtf(var_t + 1e-5f) + bet[0];
  st = (st > 0.f) ? st : 0.01f * st;
  float mx = fmaxf(si, st);
  float e0 = expf(si - mx), e1 = expf(st - mx);
  float inv = 1.f / (e0 + e1);
  out[i] = (e0 * inv) * p[i] + (e1 * inv) * q[i] + ue[i];
}

// ---------------------------------------------------------------------------
extern "C" void kernel_launch(void* const* d_in, const int* in_sizes, int n_in,
                              void* d_out, int out_size, void* d_ws,
                              size_t ws_size, hipStream_t stream) {
  const float* user_emb = (const float*)d_in[0];
  const float* item_emb = (const float*)d_in[1];
  const int* rate_src = (const int*)d_in[2];
  const int* rate_dst = (const int*)d_in[3];
  const int* rb_src = (const int*)d_in[4];
  const int* rb_dst = (const int*)d_in[5];
  const int* tr_src = (const int*)d_in[6];
  const int* tr_dst = (const int*)d_in[7];
  const float* rate_Wsrc = (const float*)d_in[8];
  const float* rate_bsrc = (const float*)d_in[9];
  const float* rate_Wdst = (const float*)d_in[10];
  const float* rate_bdst = (const float*)d_in[11];
  const float* rate_attn = (const float*)d_in[12];
  const float* rate_bias = (const float*)d_in[13];
  const float* rb_Wsrc = (const float*)d_in[14];
  const float* rb_bsrc = (const float*)d_in[15];
  const float* rb_Wdst = (const float*)d_in[16];
  const float* rb_bdst = (const float*)d_in[17];
  const float* rb_attn = (const float*)d_in[18];
  const float* rb_bias = (const float*)d_in[19];
  const float* tr_Wsrc = (const float*)d_in[20];
  const float* tr_bsrc = (const float*)d_in[21];
  const float* tr_Wdst = (const float*)d_in[22];
  const float* tr_bdst = (const float*)d_in[23];
  const float* tr_attn = (const float*)d_in[24];
  const float* tr_bias = (const float*)d_in[25];
  const float* inf_W1 = (const float*)d_in[26];
  const float* inf_b1 = (const float*)d_in[27];
  const float* inf_W2 = (const float*)d_in[28];
  const float* inf_b2 = (const float*)d_in[29];
  const float* inf_g = (const float*)d_in[30];
  const float* inf_be = (const float*)d_in[31];
  const float* int_W1 = (const float*)d_in[32];
  const float* int_b1 = (const float*)d_in[33];
  const float* int_W2 = (const float*)d_in[34];
  const float* int_b2 = (const float*)d_in[35];
  const float* int_g = (const float*)d_in[36];
  const float* int_be = (const float*)d_in[37];

  const int NU = in_sizes[0] / 64;
  const int NI = in_sizes[1] / 64;
  const int E = in_sizes[2];
  const size_t MX = (size_t)((NU > NI) ? NU : NI);

  // workspace carve-up (256B aligned)
  char* ws = (char*)d_ws;
  size_t off = 0;
  auto alloc = [&](size_t bytes) -> void* {
    void* pp = ws + off;
    off += (bytes + 255) & ~(size_t)255;
    return pp;
  };
  float* fs = (float*)alloc(MX * 64 * 4);
  float* fd = (float*)alloc(MX * 64 * 4);
  float* q_acc = (float*)alloc((size_t)NU * 64 * 4);
  float* e_buf = (float*)alloc((size_t)E * 4);
  unsigned* m_buf = (unsigned*)alloc(MX * 4);
  float* z_buf = (float*)alloc(MX * 4);
  float* h_inf = (float*)alloc((size_t)NU * 4);
  float* h_int = (float*)alloc((size_t)NU * 4);
  float* wbuf = (float*)alloc(272 * 4);
  double* stats = (double*)alloc(4 * 8);
  double* partials = (double*)alloc((size_t)FH_BLOCKS * 4 * 8);

  float* p_acc = (float*)d_out;                       // user region of output
  float* item_acc = (float*)d_out + (size_t)NU * 64;  // item region

  const int projThreads = 256;
  auto projGrid = [](int n) { return (n + 63) / 64; };
  const int edgeBlocks = (E + 3) / 4;  // 4 waves/block, 1 edge/wave
  auto elemGrid = [](int total) { return (total + 255) / 256; };

  // zero accumulators
  hipMemsetAsync(d_out, 0, (size_t)out_size * sizeof(float), stream);
  hipMemsetAsync(q_acc, 0, (size_t)NU * 64 * 4, stream);

  weff_kernel<<<1, 256, 0, stream>>>(inf_W1, inf_b1, inf_W2, inf_b2, int_W1,
                                     int_b1, int_W2, int_b2, wbuf);

  // ---- trust: user -> user  => p_hair (in d_out user region) ----
  proj64_kernel<<<projGrid(NU), projThreads, 0, stream>>>(user_emb, tr_Wsrc,
                                                          tr_bsrc, fs, NU);
  proj64_kernel<<<projGrid(NU), projThreads, 0, stream>>>(user_emb, tr_Wdst,
                                                          tr_bdst, fd, NU);
  hipMemsetAsync(m_buf, 0, MX * 4, stream);
  hipMemsetAsync(z_buf, 0, MX * 4, stream);
  edge_scores_kernel<<<edgeBlocks, 256, 0, stream>>>(fs, fd, tr_src, tr_dst,
                                                     tr_attn, e_buf, m_buf, E);
  edge_accum_kernel<<<edgeBlocks, 256, 0, stream>>>(fs, tr_src, tr_dst, e_buf,
                                                    m_buf, z_buf, p_acc, E);
  finalize_kernel<<<elemGrid(NU * 64), 256, 0, stream>>>(
      p_acc, z_buf, tr_bias, nullptr, p_acc, NU * 64);

  // ---- ratedby: item -> user  => q_hair ----
  proj64_kernel<<<projGrid(NI), projThreads, 0, stream>>>(item_emb, rb_Wsrc,
                                                          rb_bsrc, fs, NI);
  proj64_kernel<<<projGrid(NU), projThreads, 0, stream>>>(user_emb, rb_Wdst,
                                                          rb_bdst, fd, NU);
  hipMemsetAsync(m_buf, 0, MX * 4, stream);
  hipMemsetAsync(z_buf, 0, MX * 4, stream);
  edge_scores_kernel<<<edgeBlocks, 256, 0, stream>>>(fs, fd, rb_src, rb_dst,
                                                     rb_attn, e_buf, m_buf, E);
  edge_accum_kernel<<<edgeBlocks, 256, 0, stream>>>(fs, rb_src, rb_dst, e_buf,
                                                    m_buf, z_buf, q_acc, E);
  finalize_kernel<<<elemGrid(NU * 64), 256, 0, stream>>>(
      q_acc, z_buf, rb_bias, nullptr, q_acc, NU * 64);

  // ---- rate: user -> item  => item_out (d_out item region) ----
  proj64_kernel<<<projGrid(NU), projThreads, 0, stream>>>(user_emb, rate_Wsrc,
                                                          rate_bsrc, fs, NU);
  proj64_kernel<<<projGrid(NI), projThreads, 0, stream>>>(item_emb, rate_Wdst,
                                                          rate_bdst, fd, NI);
  hipMemsetAsync(m_buf, 0, MX * 4, stream);
  hipMemsetAsync(z_buf, 0, MX * 4, stream);
  edge_scores_kernel<<<edgeBlocks, 256, 0, stream>>>(
      fs, fd, rate_src, rate_dst, rate_attn, e_buf, m_buf, E);
  edge_accum_kernel<<<edgeBlocks, 256, 0, stream>>>(
      fs, rate_src, rate_dst, e_buf, m_buf, z_buf, item_acc, E);
  finalize_kernel<<<elemGrid(NI * 64), 256, 0, stream>>>(
      item_acc, z_buf, rate_bias, item_emb, item_acc, NI * 64);

  // ---- fusion ----
  fuse_h_kernel<<<FH_BLOCKS, 256, 0, stream>>>(user_emb, p_acc, q_acc, wbuf,
                                               h_inf, h_int, partials, NU);
  reduce_stats_kernel<<<1, 256, 0, stream>>>(partials, stats, FH_BLOCKS);
  fuse_out_kernel<<<elemGrid(NU * 64), 256, 0, stream>>>(
      user_emb, p_acc, q_acc, h_inf, h_int, stats, inf_g, inf_be, int_g,
      int_be, (float*)d_out, NU);
}

// Round 4
// 1287.096 us; speedup vs baseline: 3.3956x; 1.5521x over previous
//
#include <hip/hip_runtime.h>
#include <cstdint>

// ---------------------------------------------------------------------------
// DiffusionLayer: 3x GATv2 (rate: user->item, ratedby: item->user,
// trust: user->user) + attention-gated fusion. All f32, D = 64.
//
// R4: push-atomic edge passes replaced by device-built CSR + pull-based
//     fused row kernel with online softmax (flash-style).
//     R3 profile: edge_accum x3 = 816 us (41%), WRITE_SIZE 288 MB/dispatch
//     (64M f32 atomics write through the coherence point; acc is only 51 MB),
//     21.8% HBM / 21% VALU -> atomic-bound, not roofline-bound.
//     This removes ALL float atomics, reads fs[src] once per edge (was 2x),
//     and writes each output row exactly once (bias/residual folded in).
// ---------------------------------------------------------------------------

#define D 64
#define FH_BLOCKS 1024  // fuse_h grid; partials reduced by reduce_stats_kernel

__device__ __forceinline__ float waveReduceSum(float v) {
#pragma unroll
  for (int off = 32; off > 0; off >>= 1) v += __shfl_xor(v, off, 64);
  return v;
}

// ---- projection: Y = X @ W + b;  X[N,64], W[64,64] row-major, b[64] -------
__global__ __launch_bounds__(256) void proj64_kernel(
    const float* __restrict__ X, const float* __restrict__ W,
    const float* __restrict__ b, float* __restrict__ Y, int N) {
  __shared__ __align__(16) float Ws[64 * 64];
  __shared__ float Xs[64][66];
  const int t = threadIdx.x;
  const int row0 = blockIdx.x * 64;

#pragma unroll
  for (int i = 0; i < 16; ++i) Ws[t + i * 256] = W[t + i * 256];
#pragma unroll
  for (int i = 0; i < 16; ++i) {
    int idx = t + i * 256;  // 0..4095
    int r = idx >> 6, k = idx & 63;
    int gr = row0 + r;
    Xs[r][k] = (gr < N) ? X[gr * 64 + k] : 0.f;
  }
  __syncthreads();

  const int jt = (t & 15) * 4;  // column group (4 cols)
  const int rt = (t >> 4) * 4;  // row group (4 rows)
  float4 bb = *reinterpret_cast<const float4*>(b + jt);
  float a00 = bb.x, a01 = bb.y, a02 = bb.z, a03 = bb.w;
  float a10 = bb.x, a11 = bb.y, a12 = bb.z, a13 = bb.w;
  float a20 = bb.x, a21 = bb.y, a22 = bb.z, a23 = bb.w;
  float a30 = bb.x, a31 = bb.y, a32 = bb.z, a33 = bb.w;

#pragma unroll 8
  for (int k = 0; k < 64; ++k) {
    float4 w4 = *reinterpret_cast<const float4*>(&Ws[k * 64 + jt]);
    float x0 = Xs[rt + 0][k];
    float x1 = Xs[rt + 1][k];
    float x2 = Xs[rt + 2][k];
    float x3 = Xs[rt + 3][k];
    a00 += x0 * w4.x; a01 += x0 * w4.y; a02 += x0 * w4.z; a03 += x0 * w4.w;
    a10 += x1 * w4.x; a11 += x1 * w4.y; a12 += x1 * w4.z; a13 += x1 * w4.w;
    a20 += x2 * w4.x; a21 += x2 * w4.y; a22 += x2 * w4.z; a23 += x2 * w4.w;
    a30 += x3 * w4.x; a31 += x3 * w4.y; a32 += x3 * w4.z; a33 += x3 * w4.w;
  }

  float4 o0 = {a00, a01, a02, a03};
  float4 o1 = {a10, a11, a12, a13};
  float4 o2 = {a20, a21, a22, a23};
  float4 o3 = {a30, a31, a32, a33};
  int gr = row0 + rt;
  if (gr + 0 < N) *reinterpret_cast<float4*>(&Y[(gr + 0) * 64 + jt]) = o0;
  if (gr + 1 < N) *reinterpret_cast<float4*>(&Y[(gr + 1) * 64 + jt]) = o1;
  if (gr + 2 < N) *reinterpret_cast<float4*>(&Y[(gr + 2) * 64 + jt]) = o2;
  if (gr + 3 < N) *reinterpret_cast<float4*>(&Y[(gr + 3) * 64 + jt]) = o3;
}

// ============================ CSR construction =============================

__global__ __launch_bounds__(256) void hist_kernel(
    const int* __restrict__ dst, int* __restrict__ counts, int E) {
  for (int i = blockIdx.x * 256 + threadIdx.x; i < E; i += gridDim.x * 256)
    atomicAdd(&counts[dst[i]], 1);
}

// per-chunk (1024) inclusive scan; writes incl[] and chunk totals
__global__ __launch_bounds__(1024) void scan_chunk_kernel(
    const int* __restrict__ counts, int* __restrict__ incl,
    int* __restrict__ chunk_tot, int N) {
  __shared__ int sh[1024];
  int t = threadIdx.x;
  int i = blockIdx.x * 1024 + t;
  int x = (i < N) ? counts[i] : 0;
  sh[t] = x;
  __syncthreads();
#pragma unroll
  for (int off = 1; off < 1024; off <<= 1) {
    int v = (t >= off) ? sh[t - off] : 0;
    __syncthreads();
    sh[t] += v;
    __syncthreads();
  }
  if (i < N) incl[i] = sh[t];
  if (t == 1023) chunk_tot[blockIdx.x] = sh[t];
}

// single block: exclusive scan of chunk totals (nchunks <= 1024)
__global__ __launch_bounds__(1024) void scan_tops_kernel(
    const int* __restrict__ chunk_tot, int* __restrict__ chunk_off,
    int nchunks) {
  __shared__ int sh[1024];
  int t = threadIdx.x;
  int x = (t < nchunks) ? chunk_tot[t] : 0;
  sh[t] = x;
  __syncthreads();
#pragma unroll
  for (int off = 1; off < 1024; off <<= 1) {
    int v = (t >= off) ? sh[t - off] : 0;
    __syncthreads();
    sh[t] += v;
    __syncthreads();
  }
  if (t < nchunks) chunk_off[t] = sh[t] - x;  // exclusive
}

// row_ptr[i+1] = incl[i] + chunk_off[i>>10]; row_ptr[0] = 0; next = row_ptr
__global__ __launch_bounds__(256) void finalize_ptr_kernel(
    const int* __restrict__ incl, const int* __restrict__ chunk_off,
    int* __restrict__ row_ptr, int* __restrict__ next, int N) {
  int i = blockIdx.x * 256 + threadIdx.x;
  if (i >= N) return;
  int v = incl[i] + chunk_off[i >> 10];
  row_ptr[i + 1] = v;
  if (i == 0) row_ptr[0] = 0;
}

__global__ __launch_bounds__(256) void copy_ptr_kernel(
    const int* __restrict__ row_ptr, int* __restrict__ next, int N) {
  int i = blockIdx.x * 256 + threadIdx.x;
  if (i < N) next[i] = row_ptr[i];
}

__global__ __launch_bounds__(256) void scatter_kernel(
    const int* __restrict__ src, const int* __restrict__ dst,
    int* __restrict__ next, int* __restrict__ esrc, int E) {
  for (int i = blockIdx.x * 256 + threadIdx.x; i < E; i += gridDim.x * 256) {
    int d = dst[i];
    int pos = atomicAdd(&next[d], 1);
    esrc[pos] = src[i];
  }
}

// ================= fused pull-based GATv2 row kernel =======================
// One wave per dst row. Online softmax: per edge gather fs[src] once,
// score, rescale running (m, z, acc). Writes out = acc/z + bias (+resid).
__global__ __launch_bounds__(256) void gat_row_kernel(
    const float* __restrict__ fs, const float* __restrict__ fd,
    const int* __restrict__ row_ptr, const int* __restrict__ esrc,
    const float* __restrict__ attn, const float* __restrict__ bias,
    const float* __restrict__ resid, float* __restrict__ out, int Nd) {
  const int lane = threadIdx.x & 63;
  const int d = (blockIdx.x * 256 + threadIdx.x) >> 6;
  if (d >= Nd) return;

  const float aw = attn[lane];
  const float fdv = fd[d * 64 + lane];
  const int jbeg = row_ptr[d];
  const int jend = row_ptr[d + 1];

  float m = -3.402823e38f, z = 0.f, acc = 0.f;
  for (int j = jbeg; j < jend; ++j) {
    int s = esrc[j];  // wave-uniform broadcast load
    float fsv = fs[s * 64 + lane];
    float v = fsv + fdv;
    v = (v > 0.f) ? v : 0.2f * v;
    v = waveReduceSum(v * aw);  // all lanes hold e_j
    float mn = fmaxf(m, v);
    float scale = __expf(m - mn);   // first iter: exp(-inf) = 0
    float w = __expf(v - mn);
    z = z * scale + w;
    acc = acc * scale + w * fsv;
    m = mn;
  }
  float inv = (z > 0.f) ? 1.f / z : 0.f;
  float o = acc * inv + bias[lane];
  if (resid) o += resid[d * 64 + lane];
  out[d * 64 + lane] = o;
}

// ---- collapse Linear(128,128)->Linear(128,1) into one 128-vector ----------
// wbuf layout: [0..127]=w_inf, [128]=c_inf, [130..257]=w_int, [258]=c_int
__global__ __launch_bounds__(256) void weff_kernel(
    const float* __restrict__ W1i, const float* __restrict__ b1i,
    const float* __restrict__ W2i, const float* __restrict__ b2i,
    const float* __restrict__ W1t, const float* __restrict__ b1t,
    const float* __restrict__ W2t, const float* __restrict__ b2t,
    float* __restrict__ wbuf) {
  int t = threadIdx.x;
  const float* W1 = (t < 128) ? W1i : W1t;
  const float* W2 = (t < 128) ? W2i : W2t;
  int i = t & 127;
  int base = (t < 128) ? 0 : 130;
  float s = 0.f;
  for (int j = 0; j < 128; ++j) s += W1[i * 128 + j] * W2[j];
  wbuf[base + i] = s;
  if (i == 0) {
    const float* b1 = (t < 128) ? b1i : b1t;
    const float* b2 = (t < 128) ? b2i : b2t;
    float c = b2[0];
    for (int j = 0; j < 128; ++j) c += b1[j] * W2[j];
    wbuf[base + 128] = c;
  }
}

// ---- h_inf/h_int per user + per-block BN partial sums (NO atomics) --------
__global__ __launch_bounds__(256) void fuse_h_kernel(
    const float* __restrict__ ue, const float* __restrict__ p,
    const float* __restrict__ q, const float* __restrict__ wbuf,
    float* __restrict__ h_inf, float* __restrict__ h_int,
    double* __restrict__ partials, int NU) {
  const int lane = threadIdx.x & 63;
  const int wv = threadIdx.x >> 6;
  const int wave = blockIdx.x * 4 + wv;
  const int nwaves = gridDim.x * 4;

  const float wi_u = wbuf[lane];
  const float wi_p = wbuf[64 + lane];
  const float wt_u = wbuf[130 + lane];
  const float wt_q = wbuf[194 + lane];
  const float ci = wbuf[128];
  const float ct = wbuf[258];

  double s0 = 0., s1 = 0., s2 = 0., s3 = 0.;
  for (int u = wave; u < NU; u += nwaves) {
    float uv = ue[u * 64 + lane];
    float hi = uv * wi_u + p[u * 64 + lane] * wi_p;
    float ht = uv * wt_u + q[u * 64 + lane] * wt_q;
    hi = waveReduceSum(hi) + ci;
    ht = waveReduceSum(ht) + ct;
    if (lane == 0) {
      h_inf[u] = hi;
      h_int[u] = ht;
    }
    s0 += (double)hi;
    s1 += (double)hi * (double)hi;
    s2 += (double)ht;
    s3 += (double)ht * (double)ht;
  }

  __shared__ double sh[4][4];
  if (lane == 0) {
    sh[wv][0] = s0;
    sh[wv][1] = s1;
    sh[wv][2] = s2;
    sh[wv][3] = s3;
  }
  __syncthreads();
  if (threadIdx.x < 4) {
    int k = threadIdx.x;
    partials[blockIdx.x * 4 + k] = sh[0][k] + sh[1][k] + sh[2][k] + sh[3][k];
  }
}

__global__ __launch_bounds__(256) void reduce_stats_kernel(
    const double* __restrict__ partials, double* __restrict__ stats,
    int nblocks) {
  int k = threadIdx.x & 3;
  int bstart = threadIdx.x >> 2;  // 0..63
  double s = 0.;
  for (int b = bstart; b < nblocks; b += 64) s += partials[b * 4 + k];
  __shared__ double sh[256];
  sh[threadIdx.x] = s;
  __syncthreads();
  if (threadIdx.x < 4) {
    double acc = 0.;
    for (int i = 0; i < 64; ++i) acc += sh[i * 4 + threadIdx.x];
    stats[threadIdx.x] = acc;
  }
}

// ---- final: BN + leaky + 2-way softmax + gated sum + residual -------------
__global__ __launch_bounds__(256) void fuse_out_kernel(
    const float* __restrict__ ue, const float* __restrict__ p,
    const float* __restrict__ q, const float* __restrict__ h_inf,
    const float* __restrict__ h_int, const double* __restrict__ stats,
    const float* __restrict__ gi, const float* __restrict__ bei,
    const float* __restrict__ gt, const float* __restrict__ bet,
    float* __restrict__ out, int NU) {
  int i = blockIdx.x * 256 + threadIdx.x;
  if (i >= NU * 64) return;
  int u = i >> 6;
  double invN = 1.0 / (double)NU;
  float mu_i = (float)(stats[0] * invN);
  float var_i = (float)(stats[1] * invN) - mu_i * mu_i;
  float mu_t = (float)(stats[2] * invN);
  float var_t = (float)(stats[3] * invN) - mu_t * mu_t;
  float si = gi[0] * (h_inf[u] - mu_i) / sqrtf(var_i + 1e-5f) + bei[0];
  si = (si > 0.f) ? si : 0.01f * si;
  float st = gt[0] * (h_int[u] - mu_t) / sqrtf(var_t + 1e-5f) + bet[0];
  st = (st > 0.f) ? st : 0.01f * st;
  float mx = fmaxf(si, st);
  float e0 = expf(si - mx), e1 = expf(st - mx);
  float inv = 1.f / (e0 + e1);
  out[i] = (e0 * inv) * p[i] + (e1 * inv) * q[i] + ue[i];
}

// ---------------------------------------------------------------------------
extern "C" void kernel_launch(void* const* d_in, const int* in_sizes, int n_in,
                              void* d_out, int out_size, void* d_ws,
                              size_t ws_size, hipStream_t stream) {
  const float* user_emb = (const float*)d_in[0];
  const float* item_emb = (const float*)d_in[1];
  const int* rate_src = (const int*)d_in[2];
  const int* rate_dst = (const int*)d_in[3];
  const int* rb_src = (const int*)d_in[4];
  const int* rb_dst = (const int*)d_in[5];
  const int* tr_src = (const int*)d_in[6];
  const int* tr_dst = (const int*)d_in[7];
  const float* rate_Wsrc = (const float*)d_in[8];
  const float* rate_bsrc = (const float*)d_in[9];
  const float* rate_Wdst = (const float*)d_in[10];
  const float* rate_bdst = (const float*)d_in[11];
  const float* rate_attn = (const float*)d_in[12];
  const float* rate_bias = (const float*)d_in[13];
  const float* rb_Wsrc = (const float*)d_in[14];
  const float* rb_bsrc = (const float*)d_in[15];
  const float* rb_Wdst = (const float*)d_in[16];
  const float* rb_bdst = (const float*)d_in[17];
  const float* rb_attn = (const float*)d_in[18];
  const float* rb_bias = (const float*)d_in[19];
  const float* tr_Wsrc = (const float*)d_in[20];
  const float* tr_bsrc = (const float*)d_in[21];
  const float* tr_Wdst = (const float*)d_in[22];
  const float* tr_bdst = (const float*)d_in[23];
  const float* tr_attn = (const float*)d_in[24];
  const float* tr_bias = (const float*)d_in[25];
  const float* inf_W1 = (const float*)d_in[26];
  const float* inf_b1 = (const float*)d_in[27];
  const float* inf_W2 = (const float*)d_in[28];
  const float* inf_b2 = (const float*)d_in[29];
  const float* inf_g = (const float*)d_in[30];
  const float* inf_be = (const float*)d_in[31];
  const float* int_W1 = (const float*)d_in[32];
  const float* int_b1 = (const float*)d_in[33];
  const float* int_W2 = (const float*)d_in[34];
  const float* int_b2 = (const float*)d_in[35];
  const float* int_g = (const float*)d_in[36];
  const float* int_be = (const float*)d_in[37];

  const int NU = in_sizes[0] / 64;
  const int NI = in_sizes[1] / 64;
  const int E = in_sizes[2];
  const size_t MX = (size_t)((NU > NI) ? NU : NI);

  // workspace carve-up (256B aligned)
  char* ws = (char*)d_ws;
  size_t off = 0;
  auto alloc = [&](size_t bytes) -> void* {
    void* pp = ws + off;
    off += (bytes + 255) & ~(size_t)255;
    return pp;
  };
  float* fs = (float*)alloc(MX * 64 * 4);
  float* fd = (float*)alloc(MX * 64 * 4);
  float* q_acc = (float*)alloc((size_t)NU * 64 * 4);
  int* counts = (int*)alloc(MX * 4);
  int* incl = (int*)alloc(MX * 4);
  int* row_ptr = (int*)alloc((MX + 1) * 4);
  int* nxt = (int*)alloc(MX * 4);
  int* esrc = (int*)alloc((size_t)E * 4);
  int* chunk_tot = (int*)alloc(1024 * 4);
  int* chunk_off = (int*)alloc(1024 * 4);
  float* h_inf = (float*)alloc((size_t)NU * 4);
  float* h_int = (float*)alloc((size_t)NU * 4);
  float* wbuf = (float*)alloc(272 * 4);
  double* stats = (double*)alloc(4 * 8);
  double* partials = (double*)alloc((size_t)FH_BLOCKS * 4 * 8);

  float* p_acc = (float*)d_out;                       // user region of output
  float* item_acc = (float*)d_out + (size_t)NU * 64;  // item region

  auto projGrid = [](int n) { return (n + 63) / 64; };
  auto elemGrid = [](int total) { return (total + 255) / 256; };
  const int edgeBlocks = 2048;  // grid-stride for hist/scatter

  weff_kernel<<<1, 256, 0, stream>>>(inf_W1, inf_b1, inf_W2, inf_b2, int_W1,
                                     int_b1, int_W2, int_b2, wbuf);

  // builds CSR for (dst,N) then runs fused row kernel
  auto run_relation = [&](const float* hsrc, int Ns, const float* hdst, int Nd,
                          const int* e_src, const int* e_dst,
                          const float* Wsrc, const float* bsrc,
                          const float* Wdst, const float* bdst,
                          const float* attn, const float* bias,
                          const float* resid, float* out) {
    proj64_kernel<<<projGrid(Ns), 256, 0, stream>>>(hsrc, Wsrc, bsrc, fs, Ns);
    proj64_kernel<<<projGrid(Nd), 256, 0, stream>>>(hdst, Wdst, bdst, fd, Nd);
    hipMemsetAsync(counts, 0, (size_t)Nd * 4, stream);
    hist_kernel<<<edgeBlocks, 256, 0, stream>>>(e_dst, counts, E);
    int nchunks = (Nd + 1023) / 1024;
    scan_chunk_kernel<<<nchunks, 1024, 0, stream>>>(counts, incl, chunk_tot,
                                                    Nd);
    scan_tops_kernel<<<1, 1024, 0, stream>>>(chunk_tot, chunk_off, nchunks);
    finalize_ptr_kernel<<<elemGrid(Nd), 256, 0, stream>>>(incl, chunk_off,
                                                          row_ptr, nxt, Nd);
    copy_ptr_kernel<<<elemGrid(Nd), 256, 0, stream>>>(row_ptr, nxt, Nd);
    scatter_kernel<<<edgeBlocks, 256, 0, stream>>>(e_src, e_dst, nxt, esrc, E);
    gat_row_kernel<<<(Nd + 3) / 4, 256, 0, stream>>>(fs, fd, row_ptr, esrc,
                                                     attn, bias, resid, out,
                                                     Nd);
  };

  // trust: user -> user  => p_hair (d_out user region)
  run_relation(user_emb, NU, user_emb, NU, tr_src, tr_dst, tr_Wsrc, tr_bsrc,
               tr_Wdst, tr_bdst, tr_attn, tr_bias, nullptr, p_acc);
  // ratedby: item -> user  => q_hair (workspace)
  run_relation(item_emb, NI, user_emb, NU, rb_src, rb_dst, rb_Wsrc, rb_bsrc,
               rb_Wdst, rb_bdst, rb_attn, rb_bias, nullptr, q_acc);
  // rate: user -> item  => item_out (d_out item region, +item_emb residual)
  run_relation(user_emb, NU, item_emb, NI, rate_src, rate_dst, rate_Wsrc,
               rate_bsrc, rate_Wdst, rate_bdst, rate_attn, rate_bias, item_emb,
               item_acc);

  // ---- fusion ----
  fuse_h_kernel<<<FH_BLOCKS, 256, 0, stream>>>(user_emb, p_acc, q_acc, wbuf,
                                               h_inf, h_int, partials, NU);
  reduce_stats_kernel<<<1, 256, 0, stream>>>(partials, stats, FH_BLOCKS);
  fuse_out_kernel<<<elemGrid(NU * 64), 256, 0, stream>>>(
      user_emb, p_acc, q_acc, h_inf, h_int, stats, inf_g, inf_be, int_g,
      int_be, (float*)d_out, NU);
}

// Round 9
// 1055.012 us; speedup vs baseline: 4.1425x; 1.2200x over previous
//
#include <hip/hip_runtime.h>
#include <cstdint>

// ---------------------------------------------------------------------------
// DiffusionLayer: 3x GATv2 (rate: user->item, ratedby: item->user,
// trust: user->user) + attention-gated fusion. All f32, D = 64.
//
// R9 = R5 changeset + compile fix. R8 failed: FMA4 macro param named `w`
//      was substituted into the member access `a.w` (a0.w -> a0.w0).
//      Replaced macro with a hygienic inline function fma4().
// R5:  gat_row was latency-bound (R4: 152us, 17% HBM, 45% VALU, 1 gather in
//      flight/wave). Now 4x16-lane groups, float4/lane, 4 edges in flight,
//      online-softmax merged across groups by xor-16/32 butterfly.
//      CSR build batched across the 3 relations; proj64 float4 LDS reads.
// ---------------------------------------------------------------------------

#define D 64
#define FH_BLOCKS 1024

__device__ __forceinline__ float waveReduceSum(float v) {
#pragma unroll
  for (int off = 32; off > 0; off >>= 1) v += __shfl_xor(v, off, 64);
  return v;
}

__device__ __forceinline__ void fma4(float4& a, float s, const float4& b) {
  a.x += s * b.x;
  a.y += s * b.y;
  a.z += s * b.z;
  a.w += s * b.w;
}

// ---- projection: Y = X @ W + b;  X[N,64], W[64,64] row-major, b[64] -------
__global__ __launch_bounds__(256) void proj64_kernel(
    const float* __restrict__ X, const float* __restrict__ W,
    const float* __restrict__ b, float* __restrict__ Y, int N) {
  __shared__ __align__(16) float Ws[64 * 64];
  __shared__ __align__(16) float Xs[64][68];  // row stride 272B (17x16B)
  const int t = threadIdx.x;
  const int row0 = blockIdx.x * 64;

#pragma unroll
  for (int i = 0; i < 16; ++i) Ws[t + i * 256] = W[t + i * 256];
#pragma unroll
  for (int i = 0; i < 16; ++i) {
    int idx = t + i * 256;  // 0..4095
    int r = idx >> 6, k = idx & 63;
    int gr = row0 + r;
    Xs[r][k] = (gr < N) ? X[gr * 64 + k] : 0.f;
  }
  __syncthreads();

  const int jt = (t & 15) * 4;  // column group (4 cols)
  const int rt = (t >> 4) * 4;  // row group (4 rows)
  float4 a0 = *reinterpret_cast<const float4*>(b + jt);
  float4 a1 = a0, a2 = a0, a3 = a0;

#pragma unroll 4
  for (int k4 = 0; k4 < 16; ++k4) {
    float4 w0 = *reinterpret_cast<const float4*>(&Ws[(k4 * 4 + 0) * 64 + jt]);
    float4 w1 = *reinterpret_cast<const float4*>(&Ws[(k4 * 4 + 1) * 64 + jt]);
    float4 w2 = *reinterpret_cast<const float4*>(&Ws[(k4 * 4 + 2) * 64 + jt]);
    float4 w3 = *reinterpret_cast<const float4*>(&Ws[(k4 * 4 + 3) * 64 + jt]);
    float4 x0 = *reinterpret_cast<const float4*>(&Xs[rt + 0][k4 * 4]);
    float4 x1 = *reinterpret_cast<const float4*>(&Xs[rt + 1][k4 * 4]);
    float4 x2 = *reinterpret_cast<const float4*>(&Xs[rt + 2][k4 * 4]);
    float4 x3 = *reinterpret_cast<const float4*>(&Xs[rt + 3][k4 * 4]);
    fma4(a0, x0.x, w0); fma4(a0, x0.y, w1); fma4(a0, x0.z, w2); fma4(a0, x0.w, w3);
    fma4(a1, x1.x, w0); fma4(a1, x1.y, w1); fma4(a1, x1.z, w2); fma4(a1, x1.w, w3);
    fma4(a2, x2.x, w0); fma4(a2, x2.y, w1); fma4(a2, x2.z, w2); fma4(a2, x2.w, w3);
    fma4(a3, x3.x, w0); fma4(a3, x3.y, w1); fma4(a3, x3.z, w2); fma4(a3, x3.w, w3);
  }

  int gr = row0 + rt;
  if (gr + 0 < N) *reinterpret_cast<float4*>(&Y[(gr + 0) * 64 + jt]) = a0;
  if (gr + 1 < N) *reinterpret_cast<float4*>(&Y[(gr + 1) * 64 + jt]) = a1;
  if (gr + 2 < N) *reinterpret_cast<float4*>(&Y[(gr + 2) * 64 + jt]) = a2;
  if (gr + 3 < N) *reinterpret_cast<float4*>(&Y[(gr + 3) * 64 + jt]) = a3;
}

// ================== batched CSR construction (3 relations) =================
// Row space: trust rows [0,NU), ratedby rows [NU,2NU), rate rows [2NU,2NU+NI).
// Edge space: trust [0,E), ratedby [E,2E), rate [2E,3E).

__global__ __launch_bounds__(256) void hist3_kernel(
    const int* __restrict__ d0, const int* __restrict__ d1,
    const int* __restrict__ d2, int b1, int b2, int* __restrict__ counts,
    int E) {
  int stride = gridDim.x * 256;
  for (int i = blockIdx.x * 256 + threadIdx.x; i < 3 * E; i += stride) {
    int r = (i >= 2 * E) ? 2 : (i >= E ? 1 : 0);
    int j = i - r * E;
    const int* dp = (r == 0) ? d0 : (r == 1) ? d1 : d2;
    int base = (r == 0) ? 0 : (r == 1) ? b1 : b2;
    atomicAdd(&counts[dp[j] + base], 1);
  }
}

// per-chunk (1024) inclusive scan; incl may alias counts
__global__ __launch_bounds__(1024) void scan_chunk_kernel(
    const int* __restrict__ counts, int* __restrict__ incl,
    int* __restrict__ chunk_tot, int N) {
  __shared__ int sh[1024];
  int t = threadIdx.x;
  int i = blockIdx.x * 1024 + t;
  int x = (i < N) ? counts[i] : 0;
  sh[t] = x;
  __syncthreads();
#pragma unroll
  for (int off = 1; off < 1024; off <<= 1) {
    int v = (t >= off) ? sh[t - off] : 0;
    __syncthreads();
    sh[t] += v;
    __syncthreads();
  }
  if (i < N) incl[i] = sh[t];
  if (t == 1023) chunk_tot[blockIdx.x] = sh[t];
}

__global__ __launch_bounds__(1024) void scan_tops_kernel(
    const int* __restrict__ chunk_tot, int* __restrict__ chunk_off,
    int nchunks) {
  __shared__ int sh[1024];
  int t = threadIdx.x;
  int x = (t < nchunks) ? chunk_tot[t] : 0;
  sh[t] = x;
  __syncthreads();
#pragma unroll
  for (int off = 1; off < 1024; off <<= 1) {
    int v = (t >= off) ? sh[t - off] : 0;
    __syncthreads();
    sh[t] += v;
    __syncthreads();
  }
  if (t < nchunks) chunk_off[t] = sh[t] - x;  // exclusive
}

__global__ __launch_bounds__(256) void finalize_ptr_kernel(
    const int* __restrict__ incl, const int* __restrict__ chunk_off,
    int* __restrict__ row_ptr, int N) {
  int i = blockIdx.x * 256 + threadIdx.x;
  if (i >= N) return;
  row_ptr[i + 1] = incl[i] + chunk_off[i >> 10];
  if (i == 0) row_ptr[0] = 0;
}

__global__ __launch_bounds__(256) void copy_ptr_kernel(
    const int* __restrict__ row_ptr, int* __restrict__ next, int N) {
  int i = blockIdx.x * 256 + threadIdx.x;
  if (i < N) next[i] = row_ptr[i];
}

__global__ __launch_bounds__(256) void scatter3_kernel(
    const int* __restrict__ s0, const int* __restrict__ d0,
    const int* __restrict__ s1, const int* __restrict__ d1,
    const int* __restrict__ s2, const int* __restrict__ d2, int b1, int b2,
    int* __restrict__ next, int* __restrict__ esrc, int E) {
  int stride = gridDim.x * 256;
  for (int i = blockIdx.x * 256 + threadIdx.x; i < 3 * E; i += stride) {
    int r = (i >= 2 * E) ? 2 : (i >= E ? 1 : 0);
    int j = i - r * E;
    const int* dp = (r == 0) ? d0 : (r == 1) ? d1 : d2;
    const int* sp = (r == 0) ? s0 : (r == 1) ? s1 : s2;
    int base = (r == 0) ? 0 : (r == 1) ? b1 : b2;
    int pos = atomicAdd(&next[dp[j] + base], 1);
    esrc[pos] = sp[j];
  }
}

// ================= fused pull-based GATv2 row kernel =======================
// One wave per dst row; 4 groups of 16 lanes, each group owns edges
// j = jbeg+g, +4, ... with float4 channels per lane (4 gathers in flight).
// Per-group online softmax (m,z,acc); groups merged by xor-16/32 butterfly.
__global__ __launch_bounds__(256) void gat_row_kernel(
    const float* __restrict__ fs, const float* __restrict__ fd,
    const int* __restrict__ row_ptr, const int* __restrict__ esrc,
    const float* __restrict__ attn, const float* __restrict__ bias,
    const float* __restrict__ resid, float* __restrict__ out, int Nd) {
  const int lane = threadIdx.x & 63;
  const int d = (blockIdx.x * 256 + threadIdx.x) >> 6;
  if (d >= Nd) return;
  const int g = lane >> 4;        // group 0..3
  const int c = (lane & 15) * 4;  // channel base

  const float4 aw = *reinterpret_cast<const float4*>(&attn[c]);
  const float4 fdv = *reinterpret_cast<const float4*>(&fd[d * 64 + c]);
  const int jbeg = row_ptr[d];
  const int jend = row_ptr[d + 1];

  float m = -1e30f, z = 0.f;
  float4 acc = {0.f, 0.f, 0.f, 0.f};
  for (int j = jbeg + g; j < jend; j += 4) {
    int s = esrc[j];
    float4 fsv = *reinterpret_cast<const float4*>(&fs[s * 64 + c]);
    float vx = fsv.x + fdv.x; vx = (vx > 0.f) ? vx : 0.2f * vx;
    float vy = fsv.y + fdv.y; vy = (vy > 0.f) ? vy : 0.2f * vy;
    float vz = fsv.z + fdv.z; vz = (vz > 0.f) ? vz : 0.2f * vz;
    float vw = fsv.w + fdv.w; vw = (vw > 0.f) ? vw : 0.2f * vw;
    float p = vx * aw.x + vy * aw.y + vz * aw.z + vw * aw.w;
#pragma unroll
    for (int off = 1; off < 16; off <<= 1) p += __shfl_xor(p, off, 64);
    float mn = fmaxf(m, p);
    float sc = __expf(m - mn);  // first edge: exp(-1e30-p) -> 0
    float w = __expf(p - mn);
    z = z * sc + w;
    acc.x = acc.x * sc + w * fsv.x;
    acc.y = acc.y * sc + w * fsv.y;
    acc.z = acc.z * sc + w * fsv.z;
    acc.w = acc.w * sc + w * fsv.w;
    m = mn;
  }
  // merge the 4 groups (empty groups have m=-1e30, z=0 -> contribute 0)
#pragma unroll
  for (int off = 16; off < 64; off <<= 1) {
    float m_o = __shfl_xor(m, off, 64);
    float z_o = __shfl_xor(z, off, 64);
    float ax = __shfl_xor(acc.x, off, 64);
    float ay = __shfl_xor(acc.y, off, 64);
    float az = __shfl_xor(acc.z, off, 64);
    float aww = __shfl_xor(acc.w, off, 64);
    float mn = fmaxf(m, m_o);
    float s0 = __expf(m - mn), s1 = __expf(m_o - mn);
    z = z * s0 + z_o * s1;
    acc.x = acc.x * s0 + ax * s1;
    acc.y = acc.y * s0 + ay * s1;
    acc.z = acc.z * s0 + az * s1;
    acc.w = acc.w * s0 + aww * s1;
    m = mn;
  }
  if (g == 0) {
    float inv = (z > 0.f) ? 1.f / z : 0.f;
    float4 bb = *reinterpret_cast<const float4*>(&bias[c]);
    float4 o;
    o.x = acc.x * inv + bb.x;
    o.y = acc.y * inv + bb.y;
    o.z = acc.z * inv + bb.z;
    o.w = acc.w * inv + bb.w;
    if (resid) {
      float4 rr = *reinterpret_cast<const float4*>(&resid[d * 64 + c]);
      o.x += rr.x; o.y += rr.y; o.z += rr.z; o.w += rr.w;
    }
    *reinterpret_cast<float4*>(&out[d * 64 + c]) = o;
  }
}

// ---- collapse Linear(128,128)->Linear(128,1) into one 128-vector ----------
// wbuf layout: [0..127]=w_inf, [128]=c_inf, [130..257]=w_int, [258]=c_int
__global__ __launch_bounds__(256) void weff_kernel(
    const float* __restrict__ W1i, const float* __restrict__ b1i,
    const float* __restrict__ W2i, const float* __restrict__ b2i,
    const float* __restrict__ W1t, const float* __restrict__ b1t,
    const float* __restrict__ W2t, const float* __restrict__ b2t,
    float* __restrict__ wbuf) {
  int t = threadIdx.x;
  const float* W1 = (t < 128) ? W1i : W1t;
  const float* W2 = (t < 128) ? W2i : W2t;
  int i = t & 127;
  int base = (t < 128) ? 0 : 130;
  float s = 0.f;
  for (int j = 0; j < 128; ++j) s += W1[i * 128 + j] * W2[j];
  wbuf[base + i] = s;
  if (i == 0) {
    const float* b1 = (t < 128) ? b1i : b1t;
    const float* b2 = (t < 128) ? b2i : b2t;
    float c = b2[0];
    for (int j = 0; j < 128; ++j) c += b1[j] * W2[j];
    wbuf[base + 128] = c;
  }
}

// ---- h_inf/h_int per user + per-block BN partial sums (NO atomics) --------
__global__ __launch_bounds__(256) void fuse_h_kernel(
    const float* __restrict__ ue, const float* __restrict__ p,
    const float* __restrict__ q, const float* __restrict__ wbuf,
    float* __restrict__ h_inf, float* __restrict__ h_int,
    double* __restrict__ partials, int NU) {
  const int lane = threadIdx.x & 63;
  const int wv = threadIdx.x >> 6;
  const int wave = blockIdx.x * 4 + wv;
  const int nwaves = gridDim.x * 4;

  const float wi_u = wbuf[lane];
  const float wi_p = wbuf[64 + lane];
  const float wt_u = wbuf[130 + lane];
  const float wt_q = wbuf[194 + lane];
  const float ci = wbuf[128];
  const float ct = wbuf[258];

  double s0 = 0., s1 = 0., s2 = 0., s3 = 0.;
  for (int u = wave; u < NU; u += nwaves) {
    float uv = ue[u * 64 + lane];
    float hi = uv * wi_u + p[u * 64 + lane] * wi_p;
    float ht = uv * wt_u + q[u * 64 + lane] * wt_q;
    hi = waveReduceSum(hi) + ci;
    ht = waveReduceSum(ht) + ct;
    if (lane == 0) {
      h_inf[u] = hi;
      h_int[u] = ht;
    }
    s0 += (double)hi;
    s1 += (double)hi * (double)hi;
    s2 += (double)ht;
    s3 += (double)ht * (double)ht;
  }

  __shared__ double sh[4][4];
  if (lane == 0) {
    sh[wv][0] = s0;
    sh[wv][1] = s1;
    sh[wv][2] = s2;
    sh[wv][3] = s3;
  }
  __syncthreads();
  if (threadIdx.x < 4) {
    int k = threadIdx.x;
    partials[blockIdx.x * 4 + k] = sh[0][k] + sh[1][k] + sh[2][k] + sh[3][k];
  }
}

__global__ __launch_bounds__(256) void reduce_stats_kernel(
    const double* __restrict__ partials, double* __restrict__ stats,
    int nblocks) {
  int k = threadIdx.x & 3;
  int bstart = threadIdx.x >> 2;  // 0..63
  double s = 0.;
  for (int b = bstart; b < nblocks; b += 64) s += partials[b * 4 + k];
  __shared__ double sh[256];
  sh[threadIdx.x] = s;
  __syncthreads();
  if (threadIdx.x < 4) {
    double acc = 0.;
    for (int i = 0; i < 64; ++i) acc += sh[i * 4 + threadIdx.x];
    stats[threadIdx.x] = acc;
  }
}

// ---- final: BN + leaky + 2-way softmax + gated sum + residual -------------
__global__ __launch_bounds__(256) void fuse_out_kernel(
    const float* __restrict__ ue, const float* __restrict__ p,
    const float* __restrict__ q, const float* __restrict__ h_inf,
    const float* __restrict__ h_int, const double* __restrict__ stats,
    const float* __restrict__ gi, const float* __restrict__ bei,
    const float* __restrict__ gt, const float* __restrict__ bet,
    float* __restrict__ out, int NU) {
  int i = blockIdx.x * 256 + threadIdx.x;
  if (i >= NU * 64) return;
  int u = i >> 6;
  double invN = 1.0 / (double)NU;
  float mu_i = (float)(stats[0] * invN);
  float var_i = (float)(stats[1] * invN) - mu_i * mu_i;
  float mu_t = (float)(stats[2] * invN);
  float var_t = (float)(stats[3] * invN) - mu_t * mu_t;
  float si = gi[0] * (h_inf[u] - mu_i) / sqrtf(var_i + 1e-5f) + bei[0];
  si = (si > 0.f) ? si : 0.01f * si;
  float st = gt[0] * (h_int[u] - mu_t) / sqrtf(var_t + 1e-5f) + bet[0];
  st = (st > 0.f) ? st : 0.01f * st;
  float mx = fmaxf(si, st);
  float e0 = expf(si - mx), e1 = expf(st - mx);
  float inv = 1.f / (e0 + e1);
  out[i] = (e0 * inv) * p[i] + (e1 * inv) * q[i] + ue[i];
}

// ---------------------------------------------------------------------------
extern "C" void kernel_launch(void* const* d_in, const int* in_sizes, int n_in,
                              void* d_out, int out_size, void* d_ws,
                              size_t ws_size, hipStream_t stream) {
  const float* user_emb = (const float*)d_in[0];
  const float* item_emb = (const float*)d_in[1];
  const int* rate_src = (const int*)d_in[2];
  const int* rate_dst = (const int*)d_in[3];
  const int* rb_src = (const int*)d_in[4];
  const int* rb_dst = (const int*)d_in[5];
  const int* tr_src = (const int*)d_in[6];
  const int* tr_dst = (const int*)d_in[7];
  const float* rate_Wsrc = (const float*)d_in[8];
  const float* rate_bsrc = (const float*)d_in[9];
  const float* rate_Wdst = (const float*)d_in[10];
  const float* rate_bdst = (const float*)d_in[11];
  const float* rate_attn = (const float*)d_in[12];
  const float* rate_bias = (const float*)d_in[13];
  const float* rb_Wsrc = (const float*)d_in[14];
  const float* rb_bsrc = (const float*)d_in[15];
  const float* rb_Wdst = (const float*)d_in[16];
  const float* rb_bdst = (const float*)d_in[17];
  const float* rb_attn = (const float*)d_in[18];
  const float* rb_bias = (const float*)d_in[19];
  const float* tr_Wsrc = (const float*)d_in[20];
  const float* tr_bsrc = (const float*)d_in[21];
  const float* tr_Wdst = (const float*)d_in[22];
  const float* tr_bdst = (const float*)d_in[23];
  const float* tr_attn = (const float*)d_in[24];
  const float* tr_bias = (const float*)d_in[25];
  const float* inf_W1 = (const float*)d_in[26];
  const float* inf_b1 = (const float*)d_in[27];
  const float* inf_W2 = (const float*)d_in[28];
  const float* inf_b2 = (const float*)d_in[29];
  const float* inf_g = (const float*)d_in[30];
  const float* inf_be = (const float*)d_in[31];
  const float* int_W1 = (const float*)d_in[32];
  const float* int_b1 = (const float*)d_in[33];
  const float* int_W2 = (const float*)d_in[34];
  const float* int_b2 = (const float*)d_in[35];
  const float* int_g = (const float*)d_in[36];
  const float* int_be = (const float*)d_in[37];

  const int NU = in_sizes[0] / 64;
  const int NI = in_sizes[1] / 64;
  const int E = in_sizes[2];
  const size_t MX = (size_t)((NU > NI) ? NU : NI);
  const int NT = 2 * NU + NI;  // concatenated row space

  // workspace carve-up (256B aligned)
  char* ws = (char*)d_ws;
  size_t off = 0;
  auto alloc = [&](size_t bytes) -> void* {
    void* pp = ws + off;
    off += (bytes + 255) & ~(size_t)255;
    return pp;
  };
  float* fs = (float*)alloc(MX * 64 * 4);
  float* fd = (float*)alloc(MX * 64 * 4);
  float* q_acc = (float*)alloc((size_t)NU * 64 * 4);
  int* cnt = (int*)alloc((size_t)NT * 4);  // counts -> incl -> next (aliased)
  int* row_ptr = (int*)alloc(((size_t)NT + 1) * 4);
  int* esrc = (int*)alloc((size_t)3 * E * 4);
  int* chunk_tot = (int*)alloc(1024 * 4);
  int* chunk_off = (int*)alloc(1024 * 4);
  float* h_inf = (float*)alloc((size_t)NU * 4);
  float* h_int = (float*)alloc((size_t)NU * 4);
  float* wbuf = (float*)alloc(272 * 4);
  double* stats = (double*)alloc(4 * 8);
  double* partials = (double*)alloc((size_t)FH_BLOCKS * 4 * 8);

  float* p_acc = (float*)d_out;                       // user region of output
  float* item_acc = (float*)d_out + (size_t)NU * 64;  // item region

  auto projGrid = [](int n) { return (n + 63) / 64; };
  auto elemGrid = [](int total) { return (total + 255) / 256; };
  const int edgeBlocks = 2048;

  weff_kernel<<<1, 256, 0, stream>>>(inf_W1, inf_b1, inf_W2, inf_b2, int_W1,
                                     int_b1, int_W2, int_b2, wbuf);

  // ---- batched CSR build over all 3 relations ----
  hipMemsetAsync(cnt, 0, (size_t)NT * 4, stream);
  hist3_kernel<<<edgeBlocks, 256, 0, stream>>>(tr_dst, rb_dst, rate_dst, NU,
                                               2 * NU, cnt, E);
  int nchunks = (NT + 1023) / 1024;
  scan_chunk_kernel<<<nchunks, 1024, 0, stream>>>(cnt, cnt, chunk_tot, NT);
  scan_tops_kernel<<<1, 1024, 0, stream>>>(chunk_tot, chunk_off, nchunks);
  finalize_ptr_kernel<<<elemGrid(NT), 256, 0, stream>>>(cnt, chunk_off,
                                                        row_ptr, NT);
  copy_ptr_kernel<<<elemGrid(NT), 256, 0, stream>>>(row_ptr, cnt, NT);
  scatter3_kernel<<<edgeBlocks, 256, 0, stream>>>(
      tr_src, tr_dst, rb_src, rb_dst, rate_src, rate_dst, NU, 2 * NU, cnt,
      esrc, E);

  // ---- trust: user -> user  => p_hair (d_out user region) ----
  proj64_kernel<<<projGrid(NU), 256, 0, stream>>>(user_emb, tr_Wsrc, tr_bsrc,
                                                  fs, NU);
  proj64_kernel<<<projGrid(NU), 256, 0, stream>>>(user_emb, tr_Wdst, tr_bdst,
                                                  fd, NU);
  gat_row_kernel<<<(NU + 3) / 4, 256, 0, stream>>>(
      fs, fd, row_ptr, esrc, tr_attn, tr_bias, nullptr, p_acc, NU);

  // ---- ratedby: item -> user  => q_hair ----
  proj64_kernel<<<projGrid(NI), 256, 0, stream>>>(item_emb, rb_Wsrc, rb_bsrc,
                                                  fs, NI);
  proj64_kernel<<<projGrid(NU), 256, 0, stream>>>(user_emb, rb_Wdst, rb_bdst,
                                                  fd, NU);
  gat_row_kernel<<<(NU + 3) / 4, 256, 0, stream>>>(
      fs, fd, row_ptr + NU, esrc, rb_attn, rb_bias, nullptr, q_acc, NU);

  // ---- rate: user -> item  => item_out (d_out item region, +resid) ----
  proj64_kernel<<<projGrid(NU), 256, 0, stream>>>(user_emb, rate_Wsrc,
                                                  rate_bsrc, fs, NU);
  proj64_kernel<<<projGrid(NI), 256, 0, stream>>>(item_emb, rate_Wdst,
                                                  rate_bdst, fd, NI);
  gat_row_kernel<<<(NI + 3) / 4, 256, 0, stream>>>(
      fs, fd, row_ptr + 2 * NU, esrc, rate_attn, rate_bias, item_emb,
      item_acc, NI);

  // ---- fusion ----
  fuse_h_kernel<<<FH_BLOCKS, 256, 0, stream>>>(user_emb, p_acc, q_acc, wbuf,
                                               h_inf, h_int, partials, NU);
  reduce_stats_kernel<<<1, 256, 0, stream>>>(partials, stats, FH_BLOCKS);
  fuse_out_kernel<<<elemGrid(NU * 64), 256, 0, stream>>>(
      user_emb, p_acc, q_acc, h_inf, h_int, stats, inf_g, inf_be, int_g,
      int_be, (float*)d_out, NU);
}